// Round 10
// baseline (605.849 us; speedup 1.0000x reference)
//
#include <hip/hip_runtime.h>

#define H 1024
#define L 512
#define V 50257
#define NB 1024            // cooperative grid; 4 blocks/CU guaranteed
#define LOGIT_BLOCKS 2048  // fallback path only

__device__ __forceinline__ float dot4(float4 a, float4 b) {
    return a.x*b.x + a.y*b.y + a.z*b.z + a.w*b.w;
}

__device__ __forceinline__ float wave_reduce_sum(float v) {
    #pragma unroll
    for (int o = 32; o > 0; o >>= 1) v += __shfl_xor(v, o, 64);
    return v;
}

// fast grid barrier: co-residency guaranteed by cooperative launch.
// cnt must be zeroed before the dispatch (memset node, every call).
__device__ __forceinline__ void gbar(unsigned* cnt) {
    __syncthreads();
    if (threadIdx.x == 0) {
        __threadfence();   // release prior writes (device scope)
        unsigned old = __hip_atomic_fetch_add(cnt, 1u, __ATOMIC_ACQ_REL,
                                              __HIP_MEMORY_SCOPE_AGENT);
        if (old != NB - 1u) {
            unsigned v;
            do {
                __builtin_amdgcn_s_sleep(2);
                v = __hip_atomic_load(cnt, __ATOMIC_ACQUIRE, __HIP_MEMORY_SCOPE_AGENT);
            } while (v < (unsigned)NB);
        }
        __threadfence();   // invalidate L1 so post-barrier loads see fresh data
    }
    __syncthreads();
}

__global__ __launch_bounds__(256, 4)
void k_mega(const int* __restrict__ input, const float* __restrict__ hidden,
            const float* __restrict__ enc, const float* __restrict__ emb,
            const float* __restrict__ attn_w, const float* __restrict__ attn_b,
            const float* __restrict__ comb_w, const float* __restrict__ comb_b,
            const float* __restrict__ w_ih, const float* __restrict__ w_hh,
            const float* __restrict__ b_ih, const float* __restrict__ b_hh,
            const float* __restrict__ out_w, const float* __restrict__ out_b,
            float* __restrict__ out, float* __restrict__ hnew, float* __restrict__ attnw,
            float* __restrict__ scores, float* __restrict__ gh, float* __restrict__ ce,
            float* __restrict__ attn_applied, float* __restrict__ xbuf,
            float* __restrict__ mpart, float* __restrict__ spart,
            unsigned* __restrict__ bar) {
    __shared__ float s_w[512];
    __shared__ float s_acc[256];
    __shared__ float s_red[16];
    __shared__ float s_scalar;

    int t = threadIdx.x, lane = t & 63, wid = t >> 6, bid = blockIdx.x;
    size_t erow = (size_t)input[0] * H;

    // ---- stage A: scores (512) | gh = w_hh.h0 + b_hh (3072) | ce = comb_w[:,:H].e (1024)
    {
        float4 ev = ((const float4*)(emb + erow))[t];
        float4 hv = ((const float4*)hidden)[t];
        for (int task = bid; task < 4608; task += NB) {
            float acc;
            if (task < 512) {
                const float4* w = (const float4*)(attn_w + (size_t)task * (2 * H));
                acc = dot4(w[t], ev) + dot4(w[256 + t], hv);
            } else if (task < 3584) {
                int j = task - 512;
                acc = dot4(((const float4*)(w_hh + (size_t)j * H))[t], hv);
            } else {
                int h = task - 3584;
                acc = dot4(((const float4*)(comb_w + (size_t)h * (2 * H)))[t], ev);
            }
            acc = wave_reduce_sum(acc);
            if (lane == 0) s_red[wid] = acc;
            __syncthreads();
            if (t == 0) {
                float s = s_red[0] + s_red[1] + s_red[2] + s_red[3];
                if (task < 512)       scores[task] = s + attn_b[task];
                else if (task < 3584) { int j = task - 512; gh[j] = s + b_hh[j]; }
                else                  ce[task - 3584] = s;
            }
            __syncthreads();
        }
    }
    gbar(bar + 0);

    // ---- stage B: softmax(scores) -> attnw (block 0); attn_applied (blocks 0..63, 16 cols)
    if (bid < 64) {
        float s0 = scores[t], s1 = scores[t + 256];
        float m = fmaxf(s0, s1);
        #pragma unroll
        for (int o = 32; o > 0; o >>= 1) m = fmaxf(m, __shfl_xor(m, o, 64));
        if (lane == 0) s_red[wid] = m;
        __syncthreads();
        m = fmaxf(fmaxf(s_red[0], s_red[1]), fmaxf(s_red[2], s_red[3]));
        __syncthreads();
        float e0 = expf(s0 - m), e1 = expf(s1 - m);
        float ss = wave_reduce_sum(e0 + e1);
        if (lane == 0) s_red[wid] = ss;
        __syncthreads();
        ss = s_red[0] + s_red[1] + s_red[2] + s_red[3];
        float inv = 1.f / ss;
        s_w[t] = e0 * inv; s_w[t + 256] = e1 * inv;
        __syncthreads();
        if (bid == 0) { attnw[t] = s_w[t]; attnw[t + 256] = s_w[t + 256]; }
        int col = bid * 16 + (t & 15);
        int rc  = t >> 4;
        float a = 0.f;
        #pragma unroll 8
        for (int l = rc; l < 512; l += 16) a += s_w[l] * enc[(size_t)l * H + col];
        s_acc[t] = a;
        __syncthreads();
        #pragma unroll
        for (int st = 128; st >= 16; st >>= 1) {
            if (t < st) s_acc[t] += s_acc[t + st];
            __syncthreads();
        }
        if (t < 16) attn_applied[bid * 16 + t] = s_acc[t];
    }
    gbar(bar + 1);

    // ---- stage C: x[h] = relu(ce[h] + comb_w[h,H:2H].attn_applied + comb_b[h]), h = bid
    {
        float4 av = ((const float4*)attn_applied)[t];
        float acc = dot4(((const float4*)(comb_w + (size_t)bid * (2 * H) + H))[t], av);
        acc = wave_reduce_sum(acc);
        if (lane == 0) s_red[wid] = acc;
        __syncthreads();
        if (t == 0)
            xbuf[bid] = fmaxf(ce[bid] + s_red[0] + s_red[1] + s_red[2] + s_red[3]
                              + comb_b[bid], 0.f);
    }
    gbar(bar + 2);

    // ---- stage D: gi triple + GRU gating -> hnew[bid]
    {
        float4 xv = ((const float4*)xbuf)[t];
        float a0 = dot4(((const float4*)(w_ih + (size_t)bid * H))[t], xv);
        float a1 = dot4(((const float4*)(w_ih + (size_t)(H + bid) * H))[t], xv);
        float a2 = dot4(((const float4*)(w_ih + (size_t)(2 * H + bid) * H))[t], xv);
        a0 = wave_reduce_sum(a0);
        a1 = wave_reduce_sum(a1);
        a2 = wave_reduce_sum(a2);
        if (lane == 0) { s_red[wid*3] = a0; s_red[wid*3+1] = a1; s_red[wid*3+2] = a2; }
        __syncthreads();
        if (t == 0) {
            float g0 = 0.f, g1 = 0.f, g2 = 0.f;
            #pragma unroll
            for (int w2 = 0; w2 < 4; ++w2) {
                g0 += s_red[w2*3]; g1 += s_red[w2*3+1]; g2 += s_red[w2*3+2];
            }
            float r = 1.f / (1.f + expf(-(g0 + b_ih[bid] + gh[bid])));
            float z = 1.f / (1.f + expf(-(g1 + b_ih[H + bid] + gh[H + bid])));
            float n = tanhf(g2 + b_ih[2 * H + bid] + r * gh[2 * H + bid]);
            hnew[bid] = (1.f - z) * n + z * hidden[bid];
        }
    }
    gbar(bar + 3);

    // ---- stage E: logits + per-block online (m, sumexp)
    {
        float4 h4[4];
        #pragma unroll
        for (int j = 0; j < 4; ++j) h4[j] = ((const float4*)hnew)[j * 64 + lane];
        float m = -INFINITY, s = 0.f;
        int gwave = bid * 4 + wid;
        for (int r = gwave; r < V; r += NB * 4) {
            const float4* row = (const float4*)(out_w + (size_t)r * H);
            float acc = 0.f;
            #pragma unroll
            for (int j = 0; j < 4; ++j) acc += dot4(row[j * 64 + lane], h4[j]);
            acc = wave_reduce_sum(acc);
            float logit = acc + out_b[r];
            if (lane == 0) out[r] = logit;
            if (logit > m) { s = s * expf(m - logit) + 1.f; m = logit; }
            else           { s += expf(logit - m); }
        }
        if (lane == 0) { s_red[wid] = m; s_red[4 + wid] = s; }
        __syncthreads();
        if (t == 0) {
            float M = fmaxf(fmaxf(s_red[0], s_red[1]), fmaxf(s_red[2], s_red[3]));
            float S = 0.f;
            #pragma unroll
            for (int i = 0; i < 4; ++i) S += s_red[4 + i] * expf(s_red[i] - M);
            mpart[bid] = M; spart[bid] = S;
        }
    }
    gbar(bar + 4);

    // ---- stage F: merge partials (every block), subtract logZ in place
    {
        float m = -INFINITY, s = 0.f;
        for (int i = t; i < NB; i += 256) {
            float m2 = mpart[i], s2 = spart[i];
            float mm = fmaxf(m, m2);
            if (mm > -INFINITY) s = s * expf(m - mm) + s2 * expf(m2 - mm);
            m = mm;
        }
        #pragma unroll
        for (int o = 32; o > 0; o >>= 1) {
            float m2 = __shfl_xor(m, o, 64), s2 = __shfl_xor(s, o, 64);
            float mm = fmaxf(m, m2);
            if (mm > -INFINITY) s = s * expf(m - mm) + s2 * expf(m2 - mm);
            m = mm;
        }
        if (lane == 0) { s_red[wid] = m; s_red[4 + wid] = s; }
        __syncthreads();
        if (t == 0) {
            float M = fmaxf(fmaxf(s_red[0], s_red[1]), fmaxf(s_red[2], s_red[3]));
            float S = 0.f;
            #pragma unroll
            for (int i = 0; i < 4; ++i) S += s_red[4 + i] * expf(s_red[i] - M);
            s_scalar = M + logf(S);
        }
        __syncthreads();
        float logZ = s_scalar;
        for (int v = bid * 256 + t; v < V; v += NB * 256) out[v] -= logZ;
    }
}

// ---------------- fallback path (proven R4 5+1-dispatch pipeline) ----------------
__global__ void k_pre(const float* __restrict__ emb, const int* __restrict__ input,
                      const float* __restrict__ hidden, const float* __restrict__ attn_w,
                      const float* __restrict__ attn_b, const float* __restrict__ w_hh,
                      const float* __restrict__ b_hh, const float* __restrict__ comb_w,
                      float* __restrict__ scores, float* __restrict__ gh, float* __restrict__ ce) {
    __shared__ float red[4];
    int task = blockIdx.x, t = threadIdx.x, lane = t & 63, wid = t >> 6;
    size_t erow = (size_t)input[0] * H;
    float acc;
    if (task < 512) {
        const float4* w = (const float4*)(attn_w + (size_t)task * (2 * H));
        acc = dot4(w[t], ((const float4*)(emb + erow))[t])
            + dot4(w[256 + t], ((const float4*)hidden)[t]);
    } else if (task < 3584) {
        int j = task - 512;
        acc = dot4(((const float4*)(w_hh + (size_t)j * H))[t], ((const float4*)hidden)[t]);
    } else {
        int h = task - 3584;
        acc = dot4(((const float4*)(comb_w + (size_t)h * (2 * H)))[t], ((const float4*)(emb + erow))[t]);
    }
    acc = wave_reduce_sum(acc);
    if (lane == 0) red[wid] = acc;
    __syncthreads();
    if (t == 0) {
        float s = red[0] + red[1] + red[2] + red[3];
        if (task < 512)       scores[task] = s + attn_b[task];
        else if (task < 3584) { int j = task - 512; gh[j] = s + b_hh[j]; }
        else                  ce[task - 3584] = s;
    }
}

__global__ void k_attn(const float* __restrict__ scores, const float* __restrict__ enc,
                       float* __restrict__ attn_out, float* __restrict__ attn_applied) {
    __shared__ float w[512];
    __shared__ float red[4];
    __shared__ float acc_lds[256];
    __shared__ float sM, sS;
    int t = threadIdx.x, lane = t & 63, wid = t >> 6;
    float s0 = scores[t], s1 = scores[t + 256];
    float m = fmaxf(s0, s1);
    #pragma unroll
    for (int o = 32; o > 0; o >>= 1) m = fmaxf(m, __shfl_xor(m, o, 64));
    if (lane == 0) red[wid] = m;
    __syncthreads();
    if (t == 0) sM = fmaxf(fmaxf(red[0], red[1]), fmaxf(red[2], red[3]));
    __syncthreads();
    float M = sM;
    float e0 = expf(s0 - M), e1 = expf(s1 - M);
    float s = wave_reduce_sum(e0 + e1);
    if (lane == 0) red[wid] = s;
    __syncthreads();
    if (t == 0) sS = red[0] + red[1] + red[2] + red[3];
    __syncthreads();
    float inv = 1.f / sS;
    w[t] = e0 * inv; w[t + 256] = e1 * inv;
    __syncthreads();
    if (blockIdx.x == 0) { attn_out[t] = w[t]; attn_out[t + 256] = w[t + 256]; }
    int col = blockIdx.x * 16 + (t & 15);
    int rc  = t >> 4;
    float acc = 0.f;
    #pragma unroll 8
    for (int l = rc; l < 512; l += 16) acc += w[l] * enc[(size_t)l * H + col];
    acc_lds[t] = acc;
    __syncthreads();
    #pragma unroll
    for (int st = 128; st >= 16; st >>= 1) {
        if (t < st) acc_lds[t] += acc_lds[t + st];
        __syncthreads();
    }
    if (t < 16) attn_applied[blockIdx.x * 16 + t] = acc_lds[t];
}

__global__ void k_combine2(const float* __restrict__ ce, const float* __restrict__ attn_applied,
                           const float* __restrict__ comb_w, const float* __restrict__ comb_b,
                           float* __restrict__ x) {
    __shared__ float red[4];
    int h = blockIdx.x, t = threadIdx.x, lane = t & 63, wid = t >> 6;
    float acc = dot4(((const float4*)(comb_w + (size_t)h * (2 * H) + H))[t],
                     ((const float4*)attn_applied)[t]);
    acc = wave_reduce_sum(acc);
    if (lane == 0) red[wid] = acc;
    __syncthreads();
    if (t == 0)
        x[h] = fmaxf(ce[h] + red[0] + red[1] + red[2] + red[3] + comb_b[h], 0.f);
}

__global__ void k_gru2(const float* __restrict__ w_ih, const float* __restrict__ b_ih,
                       const float* __restrict__ gh, const float* __restrict__ x,
                       const float* __restrict__ hidden, float* __restrict__ hnew) {
    __shared__ float red[12];
    int h = blockIdx.x, t = threadIdx.x, lane = t & 63, wid = t >> 6;
    float4 xv = ((const float4*)x)[t];
    float a0 = dot4(((const float4*)(w_ih + (size_t)h * H))[t], xv);
    float a1 = dot4(((const float4*)(w_ih + (size_t)(H + h) * H))[t], xv);
    float a2 = dot4(((const float4*)(w_ih + (size_t)(2 * H + h) * H))[t], xv);
    a0 = wave_reduce_sum(a0);
    a1 = wave_reduce_sum(a1);
    a2 = wave_reduce_sum(a2);
    if (lane == 0) { red[wid * 3] = a0; red[wid * 3 + 1] = a1; red[wid * 3 + 2] = a2; }
    __syncthreads();
    if (t == 0) {
        float g0 = 0.f, g1 = 0.f, g2 = 0.f;
        #pragma unroll
        for (int w2 = 0; w2 < 4; ++w2) {
            g0 += red[w2 * 3]; g1 += red[w2 * 3 + 1]; g2 += red[w2 * 3 + 2];
        }
        float r = 1.f / (1.f + expf(-(g0 + b_ih[h] + gh[h])));
        float z = 1.f / (1.f + expf(-(g1 + b_ih[H + h] + gh[H + h])));
        float n = tanhf(g2 + b_ih[2 * H + h] + r * gh[2 * H + h]);
        hnew[h] = (1.f - z) * n + z * hidden[h];
    }
}

__global__ void k_logits_lse(const float* __restrict__ out_w, const float* __restrict__ out_b,
                             const float* __restrict__ hvec, float* __restrict__ logits,
                             float* __restrict__ mpart, float* __restrict__ spart) {
    __shared__ float lm[4], ls[4];
    int lane = threadIdx.x & 63, wid = threadIdx.x >> 6;
    int gwave = blockIdx.x * 4 + wid;
    const int nwaves = LOGIT_BLOCKS * 4;
    float4 h4[4];
    #pragma unroll
    for (int j = 0; j < 4; ++j) h4[j] = ((const float4*)hvec)[j * 64 + lane];
    float m = -INFINITY, s = 0.f;
    for (int r = gwave; r < V; r += nwaves) {
        const float4* row = (const float4*)(out_w + (size_t)r * H);
        float acc = 0.f;
        #pragma unroll
        for (int j = 0; j < 4; ++j) acc += dot4(row[j * 64 + lane], h4[j]);
        acc = wave_reduce_sum(acc);
        float logit = acc + out_b[r];
        if (lane == 0) logits[r] = logit;
        if (logit > m) { s = s * expf(m - logit) + 1.f; m = logit; }
        else           { s += expf(logit - m); }
    }
    if (lane == 0) { lm[wid] = m; ls[wid] = s; }
    __syncthreads();
    if (threadIdx.x == 0) {
        float M = fmaxf(fmaxf(lm[0], lm[1]), fmaxf(lm[2], lm[3]));
        float S = 0.f;
        if (M > -INFINITY) {
            #pragma unroll
            for (int i = 0; i < 4; ++i) S += ls[i] * expf(lm[i] - M);
        }
        mpart[blockIdx.x] = M; spart[blockIdx.x] = S;
    }
}

__global__ void k_finalize(const float* __restrict__ mpart, const float* __restrict__ spart,
                           float* __restrict__ out) {
    __shared__ float lm[4], ls[4];
    __shared__ float sLogZ;
    int t = threadIdx.x, lane = t & 63, wid = t >> 6;
    float m = -INFINITY, s = 0.f;
    for (int i = t; i < LOGIT_BLOCKS; i += 256) {
        float m2 = mpart[i], s2 = spart[i];
        float mm = fmaxf(m, m2);
        if (mm > -INFINITY) s = s * expf(m - mm) + s2 * expf(m2 - mm);
        m = mm;
    }
    #pragma unroll
    for (int o = 32; o > 0; o >>= 1) {
        float m2 = __shfl_xor(m, o, 64), s2 = __shfl_xor(s, o, 64);
        float mm = fmaxf(m, m2);
        if (mm > -INFINITY) s = s * expf(m - mm) + s2 * expf(m2 - mm);
        m = mm;
    }
    if (lane == 0) { lm[wid] = m; ls[wid] = s; }
    __syncthreads();
    if (t == 0) {
        float M = fmaxf(fmaxf(lm[0], lm[1]), fmaxf(lm[2], lm[3]));
        float S = 0.f;
        #pragma unroll
        for (int i = 0; i < 4; ++i) S += ls[i] * expf(lm[i] - M);
        sLogZ = M + logf(S);
    }
    __syncthreads();
    int v = blockIdx.x * 256 + t;
    if (v < V) out[v] -= sLogZ;
}

extern "C" void kernel_launch(void* const* d_in, const int* in_sizes, int n_in,
                              void* d_out, int out_size, void* d_ws, size_t ws_size,
                              hipStream_t stream) {
    const int*   input  = (const int*)  d_in[0];
    const float* hidden = (const float*)d_in[1];
    const float* enc    = (const float*)d_in[2];
    const float* emb    = (const float*)d_in[3];
    const float* attn_w = (const float*)d_in[4];
    const float* attn_b = (const float*)d_in[5];
    const float* comb_w = (const float*)d_in[6];
    const float* comb_b = (const float*)d_in[7];
    const float* w_ih   = (const float*)d_in[8];
    const float* w_hh   = (const float*)d_in[9];
    const float* b_ih   = (const float*)d_in[10];
    const float* b_hh   = (const float*)d_in[11];
    const float* out_w  = (const float*)d_in[12];
    const float* out_b  = (const float*)d_in[13];

    float* out   = (float*)d_out;            // [0, V)      log_softmax
    float* hnew  = out + V;                  // [V, V+H)    h_new
    float* attnw = out + V + H;              // [V+H, +L)   attn_weights

    float* ws           = (float*)d_ws;
    unsigned* bar       = (unsigned*)ws;     // 8 barrier counters (32 B)
    float* scores       = ws + 8;            // 512
    float* gh           = ws + 520;          // 3072
    float* ce           = ws + 3592;         // 1024
    float* attn_applied = ws + 4616;         // 1024
    float* xbuf         = ws + 5640;         // 1024
    float* mpart        = ws + 6664;         // 1024 (mega) / 2048 (fallback)
    float* spart        = ws + 8712;         // 1024 (mega) / 2048 (fallback)

    hipMemsetAsync(bar, 0, 8 * sizeof(unsigned), stream);

    void* args[] = {
        (void*)&input, (void*)&hidden, (void*)&enc, (void*)&emb,
        (void*)&attn_w, (void*)&attn_b, (void*)&comb_w, (void*)&comb_b,
        (void*)&w_ih, (void*)&w_hh, (void*)&b_ih, (void*)&b_hh,
        (void*)&out_w, (void*)&out_b,
        (void*)&out, (void*)&hnew, (void*)&attnw,
        (void*)&scores, (void*)&gh, (void*)&ce, (void*)&attn_applied,
        (void*)&xbuf, (void*)&mpart, (void*)&spart, (void*)&bar };

    hipError_t err = hipLaunchCooperativeKernel((const void*)k_mega, dim3(NB), dim3(256),
                                                args, 0, stream);
    if (err != hipSuccess) {
        // fallback: proven R4 pipeline (59.8 us)
        k_pre        <<<4608, 256, 0, stream>>>(emb, input, hidden, attn_w, attn_b,
                                                w_hh, b_hh, comb_w, scores, gh, ce);
        k_attn       <<<64, 256, 0, stream>>>(scores, enc, attnw, attn_applied);
        k_combine2   <<<1024, 256, 0, stream>>>(ce, attn_applied, comb_w, comb_b, xbuf);
        k_gru2       <<<1024, 256, 0, stream>>>(w_ih, b_ih, gh, xbuf, hidden, hnew);
        k_logits_lse <<<LOGIT_BLOCKS, 256, 0, stream>>>(out_w, out_b, hnew, out, mpart, spart);
        k_finalize   <<<(V + 255) / 256, 256, 0, stream>>>(mpart, spart, out);
    }
}

// Round 11
// 133.927 us; speedup vs baseline: 4.5237x; 4.5237x over previous
//
#include <hip/hip_runtime.h>

#define H 1024
#define L 512
#define V 50257
#define LOGIT_BLOCKS 2048   // 4 waves each -> 8192 waves = 32/CU
#define NATT 32             // attn+combine col-chunk blocks (32 cols each)

__device__ __forceinline__ float dot4(float4 a, float4 b) {
    return a.x*b.x + a.y*b.y + a.z*b.z + a.w*b.w;
}

__device__ __forceinline__ float wave_reduce_sum(float v) {
    #pragma unroll
    for (int o = 32; o > 0; o >>= 1) v += __shfl_xor(v, o, 64);
    return v;
}

// D1: scores[l] (512 blocks) + zero xacc (block 512)
__global__ void k_scores(const float* __restrict__ emb, const int* __restrict__ input,
                         const float* __restrict__ hidden, const float* __restrict__ attn_w,
                         const float* __restrict__ attn_b,
                         float* __restrict__ scores, float* __restrict__ xacc) {
    __shared__ float red[4];
    int l = blockIdx.x, t = threadIdx.x;
    if (l == 512) {
        ((float4*)xacc)[t] = make_float4(0.f, 0.f, 0.f, 0.f);
        return;
    }
    size_t erow = (size_t)input[0] * H;
    const float4* w = (const float4*)(attn_w + (size_t)l * 2 * H);
    float acc = dot4(w[t], ((const float4*)(emb + erow))[t])
              + dot4(w[256 + t], ((const float4*)hidden)[t]);
    acc = wave_reduce_sum(acc);
    if ((t & 63) == 0) red[t >> 6] = acc;
    __syncthreads();
    if (t == 0) scores[l] = red[0] + red[1] + red[2] + red[3] + attn_b[l];
}

// D2: three concurrent task families in one dispatch:
//   bid <  NATT            : softmax (replicated) -> aa[32 cols] -> xacc partial (atomicAdd)
//   NATT <= bid < NATT+3072: gh[j] = w_hh[j].h0 + b_hh[j]
//   else (1024 blocks)     : ce[h] = comb_w[h,:H].e + comb_b[h]
__global__ void k_mid(const float* __restrict__ scores, const float* __restrict__ enc,
                      const float* __restrict__ comb_w, const float* __restrict__ comb_b,
                      const float* __restrict__ hidden, const float* __restrict__ w_hh,
                      const float* __restrict__ b_hh, const float* __restrict__ emb,
                      const int* __restrict__ input,
                      float* __restrict__ attnw, float* __restrict__ xacc,
                      float* __restrict__ gh, float* __restrict__ ce) {
    __shared__ float red[4];
    int bid = blockIdx.x, t = threadIdx.x, lane = t & 63, wid = t >> 6;

    if (bid >= NATT) {
        // ---- plain GEMV rows (proven k_pre code paths) ----
        float acc;
        int task = bid - NATT;
        if (task < 3072) {
            acc = dot4(((const float4*)(w_hh + (size_t)task * H))[t],
                       ((const float4*)hidden)[t]);
        } else {
            int h = task - 3072;
            size_t erow = (size_t)input[0] * H;
            acc = dot4(((const float4*)(comb_w + (size_t)h * (2 * H)))[t],
                       ((const float4*)(emb + erow))[t]);
        }
        acc = wave_reduce_sum(acc);
        if (lane == 0) red[wid] = acc;
        __syncthreads();
        if (t == 0) {
            float s = red[0] + red[1] + red[2] + red[3];
            if (task < 3072) gh[task] = s + b_hh[task];
            else             { int h = task - 3072; ce[h] = s + comb_b[h]; }
        }
        return;
    }

    // ---- attn + combine-partial block (32 cols) ----
    __shared__ float s_w[512];
    __shared__ float s_acc[256];
    __shared__ float sM, sS;
    int c0 = bid * 32;

    // softmax over 512 scores (replicated per block; 2 KB from L2)
    float s0 = scores[t], s1 = scores[t + 256];
    float m = fmaxf(s0, s1);
    #pragma unroll
    for (int o = 32; o > 0; o >>= 1) m = fmaxf(m, __shfl_xor(m, o, 64));
    if (lane == 0) red[wid] = m;
    __syncthreads();
    if (t == 0) sM = fmaxf(fmaxf(red[0], red[1]), fmaxf(red[2], red[3]));
    __syncthreads();
    float M = sM;
    float e0 = expf(s0 - M), e1 = expf(s1 - M);
    float ssum = wave_reduce_sum(e0 + e1);
    if (lane == 0) red[wid] = ssum;
    __syncthreads();
    if (t == 0) sS = red[0] + red[1] + red[2] + red[3];
    __syncthreads();
    float inv = 1.f / sS;
    s_w[t] = e0 * inv; s_w[t + 256] = e1 * inv;
    __syncthreads();
    if (bid == 0) { attnw[t] = s_w[t]; attnw[t + 256] = s_w[t + 256]; }

    // aa[c] = sum_l w[l] * enc[l][c0+c]  (c = t&31, row-chunk rc = t>>5; 128B segments)
    {
        int c = t & 31, rc = t >> 5;
        float a = 0.f;
        #pragma unroll 8
        for (int l = rc; l < 512; l += 8) a += s_w[l] * enc[(size_t)l * H + c0 + c];
        s_acc[t] = a;
        __syncthreads();
        #pragma unroll
        for (int st = 128; st >= 32; st >>= 1) {
            if (t < st) s_acc[t] += s_acc[t + st];
            __syncthreads();
        }
        // s_acc[0..32) = aa chunk
    }

    // xacc[h] += comb_w[h, H+c0 : H+c0+32] . aa   (one row per 32-lane group)
    {
        int lane32 = t & 31;         // col within chunk
        int hw     = t >> 5;         // row-group 0..7
        float aav  = s_acc[lane32];  // broadcast-ish LDS read
        #pragma unroll 4
        for (int hrow = hw; hrow < H; hrow += 8) {
            float v = comb_w[(size_t)hrow * (2 * H) + H + c0 + lane32] * aav;
            #pragma unroll
            for (int o = 16; o > 0; o >>= 1) v += __shfl_xor(v, o, 64);
            if (lane32 == 0) atomicAdd(&xacc[hrow], v);
        }
    }
}

// D3: x = relu(xacc + ce) elementwise, then gi triple + GRU gating -> hnew[h]
__global__ void k_gru3(const float* __restrict__ w_ih, const float* __restrict__ b_ih,
                       const float* __restrict__ gh, const float* __restrict__ xacc,
                       const float* __restrict__ ce, const float* __restrict__ hidden,
                       float* __restrict__ hnew) {
    __shared__ float red[12];
    int h = blockIdx.x, t = threadIdx.x, lane = t & 63, wid = t >> 6;
    float4 xa = ((const float4*)xacc)[t];
    float4 cv = ((const float4*)ce)[t];
    float4 xv;
    xv.x = fmaxf(xa.x + cv.x, 0.f);
    xv.y = fmaxf(xa.y + cv.y, 0.f);
    xv.z = fmaxf(xa.z + cv.z, 0.f);
    xv.w = fmaxf(xa.w + cv.w, 0.f);
    float a0 = dot4(((const float4*)(w_ih + (size_t)h * H))[t], xv);
    float a1 = dot4(((const float4*)(w_ih + (size_t)(H + h) * H))[t], xv);
    float a2 = dot4(((const float4*)(w_ih + (size_t)(2 * H + h) * H))[t], xv);
    a0 = wave_reduce_sum(a0);
    a1 = wave_reduce_sum(a1);
    a2 = wave_reduce_sum(a2);
    if (lane == 0) { red[wid * 3] = a0; red[wid * 3 + 1] = a1; red[wid * 3 + 2] = a2; }
    __syncthreads();
    if (t == 0) {
        float g0 = 0.f, g1 = 0.f, g2 = 0.f;
        #pragma unroll
        for (int w2 = 0; w2 < 4; ++w2) {
            g0 += red[w2 * 3]; g1 += red[w2 * 3 + 1]; g2 += red[w2 * 3 + 2];
        }
        float r = 1.f / (1.f + expf(-(g0 + b_ih[h] + gh[h])));
        float z = 1.f / (1.f + expf(-(g1 + b_ih[H + h] + gh[H + h])));
        float n = tanhf(g2 + b_ih[2 * H + h] + r * gh[2 * H + h]);
        hnew[h] = (1.f - z) * n + z * hidden[h];
    }
}

// D4: logits + per-block online (m, sumexp) partials
__global__ void k_logits_lse(const float* __restrict__ out_w, const float* __restrict__ out_b,
                             const float* __restrict__ hvec, float* __restrict__ logits,
                             float* __restrict__ mpart, float* __restrict__ spart) {
    __shared__ float lm[4], ls[4];
    int lane = threadIdx.x & 63, wid = threadIdx.x >> 6;
    int gwave = blockIdx.x * 4 + wid;
    const int nwaves = LOGIT_BLOCKS * 4;
    float4 h4[4];
    #pragma unroll
    for (int j = 0; j < 4; ++j) h4[j] = ((const float4*)hvec)[j * 64 + lane];
    float m = -INFINITY, s = 0.f;
    for (int r = gwave; r < V; r += nwaves) {
        const float4* row = (const float4*)(out_w + (size_t)r * H);
        float acc = 0.f;
        #pragma unroll
        for (int j = 0; j < 4; ++j) acc += dot4(row[j * 64 + lane], h4[j]);
        acc = wave_reduce_sum(acc);
        float logit = acc + out_b[r];
        if (lane == 0) logits[r] = logit;
        if (logit > m) { s = s * expf(m - logit) + 1.f; m = logit; }
        else           { s += expf(logit - m); }
    }
    if (lane == 0) { lm[wid] = m; ls[wid] = s; }
    __syncthreads();
    if (threadIdx.x == 0) {
        float M = fmaxf(fmaxf(lm[0], lm[1]), fmaxf(lm[2], lm[3]));
        float S = 0.f;
        if (M > -INFINITY) {
            #pragma unroll
            for (int i = 0; i < 4; ++i) S += ls[i] * expf(lm[i] - M);
        }
        mpart[blockIdx.x] = M; spart[blockIdx.x] = S;
    }
}

// D5: every block merges the 2048 partials, then subtracts logZ in place
__global__ void k_finalize(const float* __restrict__ mpart, const float* __restrict__ spart,
                           float* __restrict__ out) {
    __shared__ float lm[4], ls[4];
    __shared__ float sLogZ;
    int t = threadIdx.x, lane = t & 63, wid = t >> 6;
    float m = -INFINITY, s = 0.f;
    for (int i = t; i < LOGIT_BLOCKS; i += 256) {
        float m2 = mpart[i], s2 = spart[i];
        float mm = fmaxf(m, m2);
        if (mm > -INFINITY) s = s * expf(m - mm) + s2 * expf(m2 - mm);
        m = mm;
    }
    #pragma unroll
    for (int o = 32; o > 0; o >>= 1) {
        float m2 = __shfl_xor(m, o, 64), s2 = __shfl_xor(s, o, 64);
        float mm = fmaxf(m, m2);
        if (mm > -INFINITY) s = s * expf(m - mm) + s2 * expf(m2 - mm);
        m = mm;
    }
    if (lane == 0) { lm[wid] = m; ls[wid] = s; }
    __syncthreads();
    if (t == 0) {
        float M = fmaxf(fmaxf(lm[0], lm[1]), fmaxf(lm[2], lm[3]));
        float S = 0.f;
        #pragma unroll
        for (int i = 0; i < 4; ++i) S += ls[i] * expf(lm[i] - M);
        sLogZ = M + logf(S);
    }
    __syncthreads();
    int v = blockIdx.x * 256 + t;
    if (v < V) out[v] -= sLogZ;
}

extern "C" void kernel_launch(void* const* d_in, const int* in_sizes, int n_in,
                              void* d_out, int out_size, void* d_ws, size_t ws_size,
                              hipStream_t stream) {
    const int*   input  = (const int*)  d_in[0];
    const float* hidden = (const float*)d_in[1];
    const float* enc    = (const float*)d_in[2];
    const float* emb    = (const float*)d_in[3];
    const float* attn_w = (const float*)d_in[4];
    const float* attn_b = (const float*)d_in[5];
    const float* comb_w = (const float*)d_in[6];
    const float* comb_b = (const float*)d_in[7];
    const float* w_ih   = (const float*)d_in[8];
    const float* w_hh   = (const float*)d_in[9];
    const float* b_ih   = (const float*)d_in[10];
    const float* b_hh   = (const float*)d_in[11];
    const float* out_w  = (const float*)d_in[12];
    const float* out_b  = (const float*)d_in[13];

    float* out   = (float*)d_out;            // [0, V)      log_softmax
    float* hnew  = out + V;                  // [V, V+H)    h_new
    float* attnw = out + V + H;              // [V+H, +L)   attn_weights

    float* ws     = (float*)d_ws;
    float* scores = ws;                      // 512
    float* gh     = ws + 512;                // 3072
    float* ce     = ws + 3584;               // 1024 (includes comb_b)
    float* xacc   = ws + 4608;               // 1024 (zeroed by D1 each call)
    float* mpart  = ws + 5632;               // 2048
    float* spart  = ws + 7680;               // 2048

    k_scores     <<<513, 256, 0, stream>>>(emb, input, hidden, attn_w, attn_b,
                                           scores, xacc);
    k_mid        <<<NATT + 3072 + 1024, 256, 0, stream>>>(scores, enc, comb_w, comb_b,
                                                          hidden, w_hh, b_hh, emb, input,
                                                          attnw, xacc, gh, ce);
    k_gru3       <<<1024, 256, 0, stream>>>(w_ih, b_ih, gh, xacc, ce, hidden, hnew);
    k_logits_lse <<<LOGIT_BLOCKS, 256, 0, stream>>>(out_w, out_b, hnew, out, mpart, spart);
    k_finalize   <<<(V + 255) / 256, 256, 0, stream>>>(mpart, spart, out);
}

// Round 12
// 62.343 us; speedup vs baseline: 9.7180x; 2.1482x over previous
//
#include <hip/hip_runtime.h>

#define H 1024
#define L 512
#define V 50257
#define LOGIT_BLOCKS 2048   // 4 waves each -> 8192 waves = 32/CU

__device__ __forceinline__ float dot4(float4 a, float4 b) {
    return a.x*b.x + a.y*b.y + a.z*b.z + a.w*b.w;
}

__device__ __forceinline__ float wave_reduce_sum(float v) {
    #pragma unroll
    for (int o = 32; o > 0; o >>= 1) v += __shfl_xor(v, o, 64);
    return v;
}

// D1: input-only GEMVs + zero xacc.
//   task <  512          : scores
//   512 <= task < 3584   : gh[j] = w_hh[j].h0 + b_hh[j]
//   3584 <= task < 4608  : ce[h] = comb_w[h,:H].e + comb_b[h]
//   task == 4608         : xacc = 0
__global__ void k_pre(const float* __restrict__ emb, const int* __restrict__ input,
                      const float* __restrict__ hidden, const float* __restrict__ attn_w,
                      const float* __restrict__ attn_b, const float* __restrict__ w_hh,
                      const float* __restrict__ b_hh, const float* __restrict__ comb_w,
                      const float* __restrict__ comb_b,
                      float* __restrict__ scores, float* __restrict__ gh,
                      float* __restrict__ ce, float* __restrict__ xacc) {
    __shared__ float red[4];
    int task = blockIdx.x, t = threadIdx.x, lane = t & 63, wid = t >> 6;
    if (task == 4608) {
        ((float4*)xacc)[t] = make_float4(0.f, 0.f, 0.f, 0.f);
        return;
    }
    size_t erow = (size_t)input[0] * H;
    float acc;
    if (task < 512) {
        const float4* w = (const float4*)(attn_w + (size_t)task * (2 * H));
        acc = dot4(w[t], ((const float4*)(emb + erow))[t])
            + dot4(w[256 + t], ((const float4*)hidden)[t]);
    } else if (task < 3584) {
        int j = task - 512;
        acc = dot4(((const float4*)(w_hh + (size_t)j * H))[t], ((const float4*)hidden)[t]);
    } else {
        int h = task - 3584;
        acc = dot4(((const float4*)(comb_w + (size_t)h * (2 * H)))[t], ((const float4*)(emb + erow))[t]);
    }
    acc = wave_reduce_sum(acc);
    if (lane == 0) red[wid] = acc;
    __syncthreads();
    if (t == 0) {
        float s = red[0] + red[1] + red[2] + red[3];
        if (task < 512)       scores[task] = s + attn_b[task];
        else if (task < 3584) { int j = task - 512; gh[j] = s + b_hh[j]; }
        else                  { int h = task - 3584; ce[h] = s + comb_b[h]; }
    }
}

// D2: softmax (replicated; block 0 writes attnw) -> 16 aa cols (R4 geometry)
//     -> parallel combine-partial: xacc[h] += comb_w2[h, c0:c0+16] . aa
//     (thread t handles rows t, t+256, t+512, t+768: 1 cache line + 1 atomic each)
__global__ void k_attn_comb(const float* __restrict__ scores, const float* __restrict__ enc,
                            const float* __restrict__ comb_w,
                            float* __restrict__ attn_out, float* __restrict__ xacc) {
    __shared__ float w[512];
    __shared__ float red[4];
    __shared__ float acc_lds[256];
    __shared__ float sM, sS;
    int t = threadIdx.x, lane = t & 63, wid = t >> 6, b = blockIdx.x;
    float s0 = scores[t], s1 = scores[t + 256];
    float m = fmaxf(s0, s1);
    #pragma unroll
    for (int o = 32; o > 0; o >>= 1) m = fmaxf(m, __shfl_xor(m, o, 64));
    if (lane == 0) red[wid] = m;
    __syncthreads();
    if (t == 0) sM = fmaxf(fmaxf(red[0], red[1]), fmaxf(red[2], red[3]));
    __syncthreads();
    float M = sM;
    float e0 = expf(s0 - M), e1 = expf(s1 - M);
    float s = wave_reduce_sum(e0 + e1);
    if (lane == 0) red[wid] = s;
    __syncthreads();
    if (t == 0) sS = red[0] + red[1] + red[2] + red[3];
    __syncthreads();
    float inv = 1.f / sS;
    w[t] = e0 * inv; w[t + 256] = e1 * inv;
    __syncthreads();
    if (b == 0) { attn_out[t] = w[t]; attn_out[t + 256] = w[t + 256]; }

    // aa for this block's 16 cols (proven R4 pattern)
    int c0  = b * 16;
    int col = c0 + (t & 15);
    int rc  = t >> 4;
    float acc = 0.f;
    #pragma unroll 8
    for (int l = rc; l < 512; l += 16) acc += w[l] * enc[(size_t)l * H + col];
    acc_lds[t] = acc;
    __syncthreads();
    #pragma unroll
    for (int st = 128; st >= 16; st >>= 1) {
        if (t < st) acc_lds[t] += acc_lds[t + st];
        __syncthreads();
    }
    // acc_lds[0..15] = aa[c0..c0+15]
    float4 aa0 = make_float4(acc_lds[0],  acc_lds[1],  acc_lds[2],  acc_lds[3]);
    float4 aa1 = make_float4(acc_lds[4],  acc_lds[5],  acc_lds[6],  acc_lds[7]);
    float4 aa2 = make_float4(acc_lds[8],  acc_lds[9],  acc_lds[10], acc_lds[11]);
    float4 aa3 = make_float4(acc_lds[12], acc_lds[13], acc_lds[14], acc_lds[15]);
    #pragma unroll
    for (int i = 0; i < 4; ++i) {
        int h = t + 256 * i;
        const float4* c2 = (const float4*)(comb_w + (size_t)h * (2 * H) + H + c0);
        float p = dot4(c2[0], aa0) + dot4(c2[1], aa1) + dot4(c2[2], aa2) + dot4(c2[3], aa3);
        atomicAdd(&xacc[h], p);
    }
}

// D3: x = relu(xacc + ce), then gi triple + GRU gating -> hnew[h]
__global__ void k_gru3(const float* __restrict__ w_ih, const float* __restrict__ b_ih,
                       const float* __restrict__ gh, const float* __restrict__ xacc,
                       const float* __restrict__ ce, const float* __restrict__ hidden,
                       float* __restrict__ hnew) {
    __shared__ float red[12];
    int h = blockIdx.x, t = threadIdx.x, lane = t & 63, wid = t >> 6;
    float4 xa = ((const float4*)xacc)[t];
    float4 cv = ((const float4*)ce)[t];
    float4 xv;
    xv.x = fmaxf(xa.x + cv.x, 0.f);
    xv.y = fmaxf(xa.y + cv.y, 0.f);
    xv.z = fmaxf(xa.z + cv.z, 0.f);
    xv.w = fmaxf(xa.w + cv.w, 0.f);
    float a0 = dot4(((const float4*)(w_ih + (size_t)h * H))[t], xv);
    float a1 = dot4(((const float4*)(w_ih + (size_t)(H + h) * H))[t], xv);
    float a2 = dot4(((const float4*)(w_ih + (size_t)(2 * H + h) * H))[t], xv);
    a0 = wave_reduce_sum(a0);
    a1 = wave_reduce_sum(a1);
    a2 = wave_reduce_sum(a2);
    if (lane == 0) { red[wid * 3] = a0; red[wid * 3 + 1] = a1; red[wid * 3 + 2] = a2; }
    __syncthreads();
    if (t == 0) {
        float g0 = 0.f, g1 = 0.f, g2 = 0.f;
        #pragma unroll
        for (int w2 = 0; w2 < 4; ++w2) {
            g0 += red[w2 * 3]; g1 += red[w2 * 3 + 1]; g2 += red[w2 * 3 + 2];
        }
        float r = 1.f / (1.f + expf(-(g0 + b_ih[h] + gh[h])));
        float z = 1.f / (1.f + expf(-(g1 + b_ih[H + h] + gh[H + h])));
        float n = tanhf(g2 + b_ih[2 * H + h] + r * gh[2 * H + h]);
        hnew[h] = (1.f - z) * n + z * hidden[h];
    }
}

// D4: logits + per-block online (m, sumexp) partials
__global__ void k_logits_lse(const float* __restrict__ out_w, const float* __restrict__ out_b,
                             const float* __restrict__ hvec, float* __restrict__ logits,
                             float* __restrict__ mpart, float* __restrict__ spart) {
    __shared__ float lm[4], ls[4];
    int lane = threadIdx.x & 63, wid = threadIdx.x >> 6;
    int gwave = blockIdx.x * 4 + wid;
    const int nwaves = LOGIT_BLOCKS * 4;
    float4 h4[4];
    #pragma unroll
    for (int j = 0; j < 4; ++j) h4[j] = ((const float4*)hvec)[j * 64 + lane];
    float m = -INFINITY, s = 0.f;
    for (int r = gwave; r < V; r += nwaves) {
        const float4* row = (const float4*)(out_w + (size_t)r * H);
        float acc = 0.f;
        #pragma unroll
        for (int j = 0; j < 4; ++j) acc += dot4(row[j * 64 + lane], h4[j]);
        acc = wave_reduce_sum(acc);
        float logit = acc + out_b[r];
        if (lane == 0) logits[r] = logit;
        if (logit > m) { s = s * expf(m - logit) + 1.f; m = logit; }
        else           { s += expf(logit - m); }
    }
    if (lane == 0) { lm[wid] = m; ls[wid] = s; }
    __syncthreads();
    if (threadIdx.x == 0) {
        float M = fmaxf(fmaxf(lm[0], lm[1]), fmaxf(lm[2], lm[3]));
        float S = 0.f;
        if (M > -INFINITY) {
            #pragma unroll
            for (int i = 0; i < 4; ++i) S += ls[i] * expf(lm[i] - M);
        }
        mpart[blockIdx.x] = M; spart[blockIdx.x] = S;
    }
}

// D5: every block merges the 2048 partials, then subtracts logZ in place
__global__ void k_finalize(const float* __restrict__ mpart, const float* __restrict__ spart,
                           float* __restrict__ out) {
    __shared__ float lm[4], ls[4];
    __shared__ float sLogZ;
    int t = threadIdx.x, lane = t & 63, wid = t >> 6;
    float m = -INFINITY, s = 0.f;
    for (int i = t; i < LOGIT_BLOCKS; i += 256) {
        float m2 = mpart[i], s2 = spart[i];
        float mm = fmaxf(m, m2);
        if (mm > -INFINITY) s = s * expf(m - mm) + s2 * expf(m2 - mm);
        m = mm;
    }
    #pragma unroll
    for (int o = 32; o > 0; o >>= 1) {
        float m2 = __shfl_xor(m, o, 64), s2 = __shfl_xor(s, o, 64);
        float mm = fmaxf(m, m2);
        if (mm > -INFINITY) s = s * expf(m - mm) + s2 * expf(m2 - mm);
        m = mm;
    }
    if (lane == 0) { lm[wid] = m; ls[wid] = s; }
    __syncthreads();
    if (t == 0) {
        float M = fmaxf(fmaxf(lm[0], lm[1]), fmaxf(lm[2], lm[3]));
        float S = 0.f;
        #pragma unroll
        for (int i = 0; i < 4; ++i) S += ls[i] * expf(lm[i] - M);
        sLogZ = M + logf(S);
    }
    __syncthreads();
    int v = blockIdx.x * 256 + t;
    if (v < V) out[v] -= sLogZ;
}

extern "C" void kernel_launch(void* const* d_in, const int* in_sizes, int n_in,
                              void* d_out, int out_size, void* d_ws, size_t ws_size,
                              hipStream_t stream) {
    const int*   input  = (const int*)  d_in[0];
    const float* hidden = (const float*)d_in[1];
    const float* enc    = (const float*)d_in[2];
    const float* emb    = (const float*)d_in[3];
    const float* attn_w = (const float*)d_in[4];
    const float* attn_b = (const float*)d_in[5];
    const float* comb_w = (const float*)d_in[6];
    const float* comb_b = (const float*)d_in[7];
    const float* w_ih   = (const float*)d_in[8];
    const float* w_hh   = (const float*)d_in[9];
    const float* b_ih   = (const float*)d_in[10];
    const float* b_hh   = (const float*)d_in[11];
    const float* out_w  = (const float*)d_in[12];
    const float* out_b  = (const float*)d_in[13];

    float* out   = (float*)d_out;            // [0, V)      log_softmax
    float* hnew  = out + V;                  // [V, V+H)    h_new
    float* attnw = out + V + H;              // [V+H, +L)   attn_weights

    float* ws     = (float*)d_ws;
    float* scores = ws;                      // 512
    float* gh     = ws + 512;                // 3072
    float* ce     = ws + 3584;               // 1024 (includes comb_b)
    float* xacc   = ws + 4608;               // 1024 (zeroed by D1 each call)
    float* mpart  = ws + 5632;               // 2048
    float* spart  = ws + 7680;               // 2048

    k_pre        <<<4609, 256, 0, stream>>>(emb, input, hidden, attn_w, attn_b,
                                            w_hh, b_hh, comb_w, comb_b, scores, gh, ce, xacc);
    k_attn_comb  <<<64, 256, 0, stream>>>(scores, enc, comb_w, attnw, xacc);
    k_gru3       <<<1024, 256, 0, stream>>>(w_ih, b_ih, gh, xacc, ce, hidden, hnew);
    k_logits_lse <<<LOGIT_BLOCKS, 256, 0, stream>>>(out_w, out_b, hnew, out, mpart, spart);
    k_finalize   <<<(V + 255) / 256, 256, 0, stream>>>(mpart, spart, out);
}

// Round 13
// 58.972 us; speedup vs baseline: 10.2735x; 1.0572x over previous
//
#include <hip/hip_runtime.h>

#define H 1024
#define L 512
#define V 50257
#define LOGIT_BLOCKS 2048   // 4 waves each -> 8192 waves = 32/CU

__device__ __forceinline__ float dot4(float4 a, float4 b) {
    return a.x*b.x + a.y*b.y + a.z*b.z + a.w*b.w;
}

__device__ __forceinline__ float wave_reduce_sum(float v) {
    #pragma unroll
    for (int o = 32; o > 0; o >>= 1) v += __shfl_xor(v, o, 64);
    return v;
}

// D1: all input-only GEMVs in one wide dispatch (R4 proven).
__global__ void k_pre(const float* __restrict__ emb, const int* __restrict__ input,
                      const float* __restrict__ hidden, const float* __restrict__ attn_w,
                      const float* __restrict__ attn_b, const float* __restrict__ w_hh,
                      const float* __restrict__ b_hh, const float* __restrict__ comb_w,
                      float* __restrict__ scores, float* __restrict__ gh, float* __restrict__ ce) {
    __shared__ float red[4];
    int task = blockIdx.x, t = threadIdx.x, lane = t & 63, wid = t >> 6;
    size_t erow = (size_t)input[0] * H;
    float acc;
    if (task < 512) {
        const float4* w = (const float4*)(attn_w + (size_t)task * (2 * H));
        acc = dot4(w[t], ((const float4*)(emb + erow))[t])
            + dot4(w[256 + t], ((const float4*)hidden)[t]);
    } else if (task < 3584) {
        int j = task - 512;
        acc = dot4(((const float4*)(w_hh + (size_t)j * H))[t], ((const float4*)hidden)[t]);
    } else {
        int h = task - 3584;
        acc = dot4(((const float4*)(comb_w + (size_t)h * (2 * H)))[t], ((const float4*)(emb + erow))[t]);
    }
    acc = wave_reduce_sum(acc);
    if (lane == 0) red[wid] = acc;
    __syncthreads();
    if (t == 0) {
        float s = red[0] + red[1] + red[2] + red[3];
        if (task < 512)       scores[task] = s + attn_b[task];
        else if (task < 3584) { int j = task - 512; gh[j] = s + b_hh[j]; }
        else                  ce[task - 3584] = s;
    }
}

// D2: softmax(scores) -> attnw (block 0); attn_applied (64 blocks x 16 cols) (R4 proven)
__global__ void k_attn(const float* __restrict__ scores, const float* __restrict__ enc,
                       float* __restrict__ attn_out, float* __restrict__ attn_applied) {
    __shared__ float w[512];
    __shared__ float red[4];
    __shared__ float acc_lds[256];
    __shared__ float sM, sS;
    int t = threadIdx.x, lane = t & 63, wid = t >> 6;
    float s0 = scores[t], s1 = scores[t + 256];
    float m = fmaxf(s0, s1);
    #pragma unroll
    for (int o = 32; o > 0; o >>= 1) m = fmaxf(m, __shfl_xor(m, o, 64));
    if (lane == 0) red[wid] = m;
    __syncthreads();
    if (t == 0) sM = fmaxf(fmaxf(red[0], red[1]), fmaxf(red[2], red[3]));
    __syncthreads();
    float M = sM;
    float e0 = expf(s0 - M), e1 = expf(s1 - M);
    float s = wave_reduce_sum(e0 + e1);
    if (lane == 0) red[wid] = s;
    __syncthreads();
    if (t == 0) sS = red[0] + red[1] + red[2] + red[3];
    __syncthreads();
    float inv = 1.f / sS;
    w[t] = e0 * inv; w[t + 256] = e1 * inv;
    __syncthreads();
    if (blockIdx.x == 0) { attn_out[t] = w[t]; attn_out[t + 256] = w[t + 256]; }
    int col = blockIdx.x * 16 + (t & 15);
    int rc  = t >> 4;
    float acc = 0.f;
    #pragma unroll 8
    for (int l = rc; l < 512; l += 16) acc += w[l] * enc[(size_t)l * H + col];
    acc_lds[t] = acc;
    __syncthreads();
    #pragma unroll
    for (int st = 128; st >= 16; st >>= 1) {
        if (t < st) acc_lds[t] += acc_lds[t + st];
        __syncthreads();
    }
    if (t < 16) attn_applied[blockIdx.x * 16 + t] = acc_lds[t];
}

// D3: x[h] = relu(ce[h] + comb_w[h, H:2H].attn_applied + comb_b[h]) (R4 proven)
__global__ void k_combine2(const float* __restrict__ ce, const float* __restrict__ attn_applied,
                           const float* __restrict__ comb_w, const float* __restrict__ comb_b,
                           float* __restrict__ x) {
    __shared__ float red[4];
    int h = blockIdx.x, t = threadIdx.x, lane = t & 63, wid = t >> 6;
    float acc = dot4(((const float4*)(comb_w + (size_t)h * (2 * H) + H))[t],
                     ((const float4*)attn_applied)[t]);
    acc = wave_reduce_sum(acc);
    if (lane == 0) red[wid] = acc;
    __syncthreads();
    if (t == 0)
        x[h] = fmaxf(ce[h] + red[0] + red[1] + red[2] + red[3] + comb_b[h], 0.f);
}

// D4: gi triple + GRU gating with precomputed gh -> hnew[h] (R4 proven)
__global__ void k_gru2(const float* __restrict__ w_ih, const float* __restrict__ b_ih,
                       const float* __restrict__ gh, const float* __restrict__ x,
                       const float* __restrict__ hidden, float* __restrict__ hnew) {
    __shared__ float red[12];
    int h = blockIdx.x, t = threadIdx.x, lane = t & 63, wid = t >> 6;
    float4 xv = ((const float4*)x)[t];
    float a0 = dot4(((const float4*)(w_ih + (size_t)h * H))[t], xv);
    float a1 = dot4(((const float4*)(w_ih + (size_t)(H + h) * H))[t], xv);
    float a2 = dot4(((const float4*)(w_ih + (size_t)(2 * H + h) * H))[t], xv);
    a0 = wave_reduce_sum(a0);
    a1 = wave_reduce_sum(a1);
    a2 = wave_reduce_sum(a2);
    if (lane == 0) { red[wid * 3] = a0; red[wid * 3 + 1] = a1; red[wid * 3 + 2] = a2; }
    __syncthreads();
    if (t == 0) {
        float g0 = 0.f, g1 = 0.f, g2 = 0.f;
        #pragma unroll
        for (int w2 = 0; w2 < 4; ++w2) {
            g0 += red[w2 * 3]; g1 += red[w2 * 3 + 1]; g2 += red[w2 * 3 + 2];
        }
        float r = 1.f / (1.f + expf(-(g0 + b_ih[h] + gh[h])));
        float z = 1.f / (1.f + expf(-(g1 + b_ih[H + h] + gh[H + h])));
        float n = tanhf(g2 + b_ih[2 * H + h] + r * gh[2 * H + h]);
        hnew[h] = (1.f - z) * n + z * hidden[h];
    }
}

// D5: logits + per-block online (m, sumexp) — TWO rows per wave-iteration for 2x MLP
__global__ void k_logits_lse(const float* __restrict__ out_w, const float* __restrict__ out_b,
                             const float* __restrict__ hvec, float* __restrict__ logits,
                             float2* __restrict__ mspart) {
    __shared__ float lm[4], ls[4];
    int lane = threadIdx.x & 63, wid = threadIdx.x >> 6;
    int gwave = blockIdx.x * 4 + wid;
    const int nwaves = LOGIT_BLOCKS * 4;
    float4 h4[4];
    #pragma unroll
    for (int j = 0; j < 4; ++j) h4[j] = ((const float4*)hvec)[j * 64 + lane];
    float m = -INFINITY, s = 0.f;
    for (int r = gwave; r < V; r += 2 * nwaves) {
        int r2 = r + nwaves;
        const float4* row1 = (const float4*)(out_w + (size_t)r * H);
        float acc1 = 0.f, acc2 = 0.f;
        // issue all 8 loads (2 rows) before any reduce
        #pragma unroll
        for (int j = 0; j < 4; ++j) acc1 += dot4(row1[j * 64 + lane], h4[j]);
        if (r2 < V) {
            const float4* row2 = (const float4*)(out_w + (size_t)r2 * H);
            #pragma unroll
            for (int j = 0; j < 4; ++j) acc2 += dot4(row2[j * 64 + lane], h4[j]);
        }
        acc1 = wave_reduce_sum(acc1);
        acc2 = wave_reduce_sum(acc2);
        float logit1 = acc1 + out_b[r];
        if (lane == 0) logits[r] = logit1;
        if (logit1 > m) { s = s * expf(m - logit1) + 1.f; m = logit1; }
        else            { s += expf(logit1 - m); }
        if (r2 < V) {
            float logit2 = acc2 + out_b[r2];
            if (lane == 0) logits[r2] = logit2;
            if (logit2 > m) { s = s * expf(m - logit2) + 1.f; m = logit2; }
            else            { s += expf(logit2 - m); }
        }
    }
    if (lane == 0) { lm[wid] = m; ls[wid] = s; }
    __syncthreads();
    if (threadIdx.x == 0) {
        float M = fmaxf(fmaxf(lm[0], lm[1]), fmaxf(lm[2], lm[3]));
        float S = 0.f;
        if (M > -INFINITY) {
            #pragma unroll
            for (int i = 0; i < 4; ++i) S += ls[i] * expf(lm[i] - M);
        }
        mspart[blockIdx.x] = make_float2(M, S);
    }
}

// D6: every block merges the 2048 packed partials, then subtracts logZ in place
__global__ void k_finalize(const float2* __restrict__ mspart, float* __restrict__ out) {
    __shared__ float lm[4], ls[4];
    __shared__ float sLogZ;
    int t = threadIdx.x, lane = t & 63, wid = t >> 6;
    float m = -INFINITY, s = 0.f;
    for (int i = t; i < LOGIT_BLOCKS; i += 256) {
        float2 p = mspart[i];
        float mm = fmaxf(m, p.x);
        if (mm > -INFINITY) s = s * expf(m - mm) + p.y * expf(p.x - mm);
        m = mm;
    }
    #pragma unroll
    for (int o = 32; o > 0; o >>= 1) {
        float m2 = __shfl_xor(m, o, 64), s2 = __shfl_xor(s, o, 64);
        float mm = fmaxf(m, m2);
        if (mm > -INFINITY) s = s * expf(m - mm) + s2 * expf(m2 - mm);
        m = mm;
    }
    if (lane == 0) { lm[wid] = m; ls[wid] = s; }
    __syncthreads();
    if (t == 0) {
        float M = fmaxf(fmaxf(lm[0], lm[1]), fmaxf(lm[2], lm[3]));
        float S = 0.f;
        #pragma unroll
        for (int i = 0; i < 4; ++i) S += ls[i] * expf(lm[i] - M);
        sLogZ = M + logf(S);
    }
    __syncthreads();
    int v = blockIdx.x * 256 + t;
    if (v < V) out[v] -= sLogZ;
}

extern "C" void kernel_launch(void* const* d_in, const int* in_sizes, int n_in,
                              void* d_out, int out_size, void* d_ws, size_t ws_size,
                              hipStream_t stream) {
    const int*   input  = (const int*)  d_in[0];
    const float* hidden = (const float*)d_in[1];
    const float* enc    = (const float*)d_in[2];
    const float* emb    = (const float*)d_in[3];
    const float* attn_w = (const float*)d_in[4];
    const float* attn_b = (const float*)d_in[5];
    const float* comb_w = (const float*)d_in[6];
    const float* comb_b = (const float*)d_in[7];
    const float* w_ih   = (const float*)d_in[8];
    const float* w_hh   = (const float*)d_in[9];
    const float* b_ih   = (const float*)d_in[10];
    const float* b_hh   = (const float*)d_in[11];
    const float* out_w  = (const float*)d_in[12];
    const float* out_b  = (const float*)d_in[13];

    float* out   = (float*)d_out;            // [0, V)      log_softmax
    float* hnew  = out + V;                  // [V, V+H)    h_new
    float* attnw = out + V + H;              // [V+H, +L)   attn_weights

    float* ws           = (float*)d_ws;
    float* scores       = ws;                // 512
    float* gh           = ws + 512;          // 3072
    float* ce           = ws + 3584;         // 1024
    float* attn_applied = ws + 4608;         // 1024
    float* xbuf         = ws + 5632;         // 1024
    float2* mspart      = (float2*)(ws + 6656); // 2048 float2

    k_pre        <<<4608, 256, 0, stream>>>(emb, input, hidden, attn_w, attn_b,
                                            w_hh, b_hh, comb_w, scores, gh, ce);
    k_attn       <<<64, 256, 0, stream>>>(scores, enc, attnw, attn_applied);
    k_combine2   <<<1024, 256, 0, stream>>>(ce, attn_applied, comb_w, comb_b, xbuf);
    k_gru2       <<<1024, 256, 0, stream>>>(w_ih, b_ih, gh, xbuf, hidden, hnew);
    k_logits_lse <<<LOGIT_BLOCKS, 256, 0, stream>>>(out_w, out_b, hnew, out, mspart);
    k_finalize   <<<(V + 255) / 256, 256, 0, stream>>>(mspart, out);
}

// Round 14
// 58.680 us; speedup vs baseline: 10.3247x; 1.0050x over previous
//
#include <hip/hip_runtime.h>

#define H 1024
#define L 512
#define V 50257
#define LOGIT_BLOCKS 2048   // 4 waves each -> 8192 waves = 32/CU

__device__ __forceinline__ float dot4(float4 a, float4 b) {
    return a.x*b.x + a.y*b.y + a.z*b.z + a.w*b.w;
}

__device__ __forceinline__ float wave_reduce_sum(float v) {
    #pragma unroll
    for (int o = 32; o > 0; o >>= 1) v += __shfl_xor(v, o, 64);
    return v;
}

// D1: all input-only GEMVs + zero attn_applied (task 4608).
__global__ void k_pre(const float* __restrict__ emb, const int* __restrict__ input,
                      const float* __restrict__ hidden, const float* __restrict__ attn_w,
                      const float* __restrict__ attn_b, const float* __restrict__ w_hh,
                      const float* __restrict__ b_hh, const float* __restrict__ comb_w,
                      float* __restrict__ scores, float* __restrict__ gh,
                      float* __restrict__ ce, float* __restrict__ attn_applied) {
    __shared__ float red[4];
    int task = blockIdx.x, t = threadIdx.x, lane = t & 63, wid = t >> 6;
    if (task == 4608) {
        ((float4*)attn_applied)[t] = make_float4(0.f, 0.f, 0.f, 0.f);
        return;
    }
    size_t erow = (size_t)input[0] * H;
    float acc;
    if (task < 512) {
        const float4* w = (const float4*)(attn_w + (size_t)task * (2 * H));
        acc = dot4(w[t], ((const float4*)(emb + erow))[t])
            + dot4(w[256 + t], ((const float4*)hidden)[t]);
    } else if (task < 3584) {
        int j = task - 512;
        acc = dot4(((const float4*)(w_hh + (size_t)j * H))[t], ((const float4*)hidden)[t]);
    } else {
        int h = task - 3584;
        acc = dot4(((const float4*)(comb_w + (size_t)h * (2 * H)))[t], ((const float4*)(emb + erow))[t]);
    }
    acc = wave_reduce_sum(acc);
    if (lane == 0) red[wid] = acc;
    __syncthreads();
    if (t == 0) {
        float s = red[0] + red[1] + red[2] + red[3];
        if (task < 512)       scores[task] = s + attn_b[task];
        else if (task < 3584) { int j = task - 512; gh[j] = s + b_hh[j]; }
        else                  ce[task - 3584] = s;
    }
}

// D2: softmax(scores) (replicated; block 0 writes attnw), then 16 aa cols over a
//     256-row half; two row-halves combine via atomicAdd (2 adds/address,
//     commutative -> deterministic). 128 blocks, 16 iters/thread.
__global__ void k_attn(const float* __restrict__ scores, const float* __restrict__ enc,
                       float* __restrict__ attn_out, float* __restrict__ attn_applied) {
    __shared__ float w[512];
    __shared__ float red[4];
    __shared__ float acc_lds[256];
    __shared__ float sM, sS;
    int t = threadIdx.x, lane = t & 63, wid = t >> 6, b = blockIdx.x;
    float s0 = scores[t], s1 = scores[t + 256];
    float m = fmaxf(s0, s1);
    #pragma unroll
    for (int o = 32; o > 0; o >>= 1) m = fmaxf(m, __shfl_xor(m, o, 64));
    if (lane == 0) red[wid] = m;
    __syncthreads();
    if (t == 0) sM = fmaxf(fmaxf(red[0], red[1]), fmaxf(red[2], red[3]));
    __syncthreads();
    float M = sM;
    float e0 = expf(s0 - M), e1 = expf(s1 - M);
    float s = wave_reduce_sum(e0 + e1);
    if (lane == 0) red[wid] = s;
    __syncthreads();
    if (t == 0) sS = red[0] + red[1] + red[2] + red[3];
    __syncthreads();
    float inv = 1.f / sS;
    w[t] = e0 * inv; w[t + 256] = e1 * inv;
    __syncthreads();
    if (b == 0) { attn_out[t] = w[t]; attn_out[t + 256] = w[t + 256]; }
    // this block's 16 cols over its 256-row half
    int col  = (b & 63) * 16 + (t & 15);
    int r0   = (b >> 6) * 256;
    int rc   = t >> 4;
    float acc = 0.f;
    #pragma unroll 8
    for (int k = 0; k < 16; ++k) {
        int l = r0 + rc + k * 16;
        acc += w[l] * enc[(size_t)l * H + col];
    }
    acc_lds[t] = acc;
    __syncthreads();
    #pragma unroll
    for (int st = 128; st >= 16; st >>= 1) {
        if (t < st) acc_lds[t] += acc_lds[t + st];
        __syncthreads();
    }
    if (t < 16) atomicAdd(&attn_applied[(b & 63) * 16 + t], acc_lds[t]);
}

// D3: x[h] = relu(ce[h] + comb_w[h, H:2H].attn_applied + comb_b[h]) (proven)
__global__ void k_combine2(const float* __restrict__ ce, const float* __restrict__ attn_applied,
                           const float* __restrict__ comb_w, const float* __restrict__ comb_b,
                           float* __restrict__ x) {
    __shared__ float red[4];
    int h = blockIdx.x, t = threadIdx.x, lane = t & 63, wid = t >> 6;
    float acc = dot4(((const float4*)(comb_w + (size_t)h * (2 * H) + H))[t],
                     ((const float4*)attn_applied)[t]);
    acc = wave_reduce_sum(acc);
    if (lane == 0) red[wid] = acc;
    __syncthreads();
    if (t == 0)
        x[h] = fmaxf(ce[h] + red[0] + red[1] + red[2] + red[3] + comb_b[h], 0.f);
}

// D4: gi triple + GRU gating with precomputed gh -> hnew[h] (proven)
__global__ void k_gru2(const float* __restrict__ w_ih, const float* __restrict__ b_ih,
                       const float* __restrict__ gh, const float* __restrict__ x,
                       const float* __restrict__ hidden, float* __restrict__ hnew) {
    __shared__ float red[12];
    int h = blockIdx.x, t = threadIdx.x, lane = t & 63, wid = t >> 6;
    float4 xv = ((const float4*)x)[t];
    float a0 = dot4(((const float4*)(w_ih + (size_t)h * H))[t], xv);
    float a1 = dot4(((const float4*)(w_ih + (size_t)(H + h) * H))[t], xv);
    float a2 = dot4(((const float4*)(w_ih + (size_t)(2 * H + h) * H))[t], xv);
    a0 = wave_reduce_sum(a0);
    a1 = wave_reduce_sum(a1);
    a2 = wave_reduce_sum(a2);
    if (lane == 0) { red[wid * 3] = a0; red[wid * 3 + 1] = a1; red[wid * 3 + 2] = a2; }
    __syncthreads();
    if (t == 0) {
        float g0 = 0.f, g1 = 0.f, g2 = 0.f;
        #pragma unroll
        for (int w2 = 0; w2 < 4; ++w2) {
            g0 += red[w2 * 3]; g1 += red[w2 * 3 + 1]; g2 += red[w2 * 3 + 2];
        }
        float r = 1.f / (1.f + expf(-(g0 + b_ih[h] + gh[h])));
        float z = 1.f / (1.f + expf(-(g1 + b_ih[H + h] + gh[H + h])));
        float n = tanhf(g2 + b_ih[2 * H + h] + r * gh[2 * H + h]);
        hnew[h] = (1.f - z) * n + z * hidden[h];
    }
}

// D5: logits + per-block online (m, sumexp) — two rows per wave-iteration (proven)
__global__ void k_logits_lse(const float* __restrict__ out_w, const float* __restrict__ out_b,
                             const float* __restrict__ hvec, float* __restrict__ logits,
                             float2* __restrict__ mspart) {
    __shared__ float lm[4], ls[4];
    int lane = threadIdx.x & 63, wid = threadIdx.x >> 6;
    int gwave = blockIdx.x * 4 + wid;
    const int nwaves = LOGIT_BLOCKS * 4;
    float4 h4[4];
    #pragma unroll
    for (int j = 0; j < 4; ++j) h4[j] = ((const float4*)hvec)[j * 64 + lane];
    float m = -INFINITY, s = 0.f;
    for (int r = gwave; r < V; r += 2 * nwaves) {
        int r2 = r + nwaves;
        const float4* row1 = (const float4*)(out_w + (size_t)r * H);
        float acc1 = 0.f, acc2 = 0.f;
        #pragma unroll
        for (int j = 0; j < 4; ++j) acc1 += dot4(row1[j * 64 + lane], h4[j]);
        if (r2 < V) {
            const float4* row2 = (const float4*)(out_w + (size_t)r2 * H);
            #pragma unroll
            for (int j = 0; j < 4; ++j) acc2 += dot4(row2[j * 64 + lane], h4[j]);
        }
        acc1 = wave_reduce_sum(acc1);
        acc2 = wave_reduce_sum(acc2);
        float logit1 = acc1 + out_b[r];
        if (lane == 0) logits[r] = logit1;
        if (logit1 > m) { s = s * expf(m - logit1) + 1.f; m = logit1; }
        else            { s += expf(logit1 - m); }
        if (r2 < V) {
            float logit2 = acc2 + out_b[r2];
            if (lane == 0) logits[r2] = logit2;
            if (logit2 > m) { s = s * expf(m - logit2) + 1.f; m = logit2; }
            else            { s += expf(logit2 - m); }
        }
    }
    if (lane == 0) { lm[wid] = m; ls[wid] = s; }
    __syncthreads();
    if (threadIdx.x == 0) {
        float M = fmaxf(fmaxf(lm[0], lm[1]), fmaxf(lm[2], lm[3]));
        float S = 0.f;
        if (M > -INFINITY) {
            #pragma unroll
            for (int i = 0; i < 4; ++i) S += ls[i] * expf(lm[i] - M);
        }
        mspart[blockIdx.x] = make_float2(M, S);
    }
}

// D6: every block merges the 2048 packed partials, then subtracts logZ in place
__global__ void k_finalize(const float2* __restrict__ mspart, float* __restrict__ out) {
    __shared__ float lm[4], ls[4];
    __shared__ float sLogZ;
    int t = threadIdx.x, lane = t & 63, wid = t >> 6;
    float m = -INFINITY, s = 0.f;
    for (int i = t; i < LOGIT_BLOCKS; i += 256) {
        float2 p = mspart[i];
        float mm = fmaxf(m, p.x);
        if (mm > -INFINITY) s = s * expf(m - mm) + p.y * expf(p.x - mm);
        m = mm;
    }
    #pragma unroll
    for (int o = 32; o > 0; o >>= 1) {
        float m2 = __shfl_xor(m, o, 64), s2 = __shfl_xor(s, o, 64);
        float mm = fmaxf(m, m2);
        if (mm > -INFINITY) s = s * expf(m - mm) + s2 * expf(m2 - mm);
        m = mm;
    }
    if (lane == 0) { lm[wid] = m; ls[wid] = s; }
    __syncthreads();
    if (t == 0) {
        float M = fmaxf(fmaxf(lm[0], lm[1]), fmaxf(lm[2], lm[3]));
        float S = 0.f;
        #pragma unroll
        for (int i = 0; i < 4; ++i) S += ls[i] * expf(lm[i] - M);
        sLogZ = M + logf(S);
    }
    __syncthreads();
    int v = blockIdx.x * 256 + t;
    if (v < V) out[v] -= sLogZ;
}

extern "C" void kernel_launch(void* const* d_in, const int* in_sizes, int n_in,
                              void* d_out, int out_size, void* d_ws, size_t ws_size,
                              hipStream_t stream) {
    const int*   input  = (const int*)  d_in[0];
    const float* hidden = (const float*)d_in[1];
    const float* enc    = (const float*)d_in[2];
    const float* emb    = (const float*)d_in[3];
    const float* attn_w = (const float*)d_in[4];
    const float* attn_b = (const float*)d_in[5];
    const float* comb_w = (const float*)d_in[6];
    const float* comb_b = (const float*)d_in[7];
    const float* w_ih   = (const float*)d_in[8];
    const float* w_hh   = (const float*)d_in[9];
    const float* b_ih   = (const float*)d_in[10];
    const float* b_hh   = (const float*)d_in[11];
    const float* out_w  = (const float*)d_in[12];
    const float* out_b  = (const float*)d_in[13];

    float* out   = (float*)d_out;            // [0, V)      log_softmax
    float* hnew  = out + V;                  // [V, V+H)    h_new
    float* attnw = out + V + H;              // [V+H, +L)   attn_weights

    float* ws           = (float*)d_ws;
    float* scores       = ws;                // 512
    float* gh           = ws + 512;          // 3072
    float* ce           = ws + 3584;         // 1024
    float* attn_applied = ws + 4608;         // 1024 (zeroed by D1, accumulated by D2)
    float* xbuf         = ws + 5632;         // 1024
    float2* mspart      = (float2*)(ws + 6656); // 2048 float2

    k_pre        <<<4609, 256, 0, stream>>>(emb, input, hidden, attn_w, attn_b,
                                            w_hh, b_hh, comb_w, scores, gh, ce, attn_applied);
    k_attn       <<<128, 256, 0, stream>>>(scores, enc, attnw, attn_applied);
    k_combine2   <<<1024, 256, 0, stream>>>(ce, attn_applied, comb_w, comb_b, xbuf);
    k_gru2       <<<1024, 256, 0, stream>>>(w_ih, b_ih, gh, xbuf, hidden, hnew);
    k_logits_lse <<<LOGIT_BLOCKS, 256, 0, stream>>>(out_w, out_b, hnew, out, mspart);
    k_finalize   <<<(V + 255) / 256, 256, 0, stream>>>(mspart, out);
}